// Round 6
// baseline (393.441 us; speedup 1.0000x reference)
//
#include <hip/hip_runtime.h>
#include <hip/hip_bf16.h>

// Round 6: split per-stage kernels + packed-FP32 inner loop (v_pk_fma_f32).
//   conv1: x(f32) -> h1(bf16); conv2: h1 -> h2(bf16); conv3+pool: h2 -> feat;
//   mlp: feat -> softmax. Fused round-3 fallback if ws_size too small.
// Inner loop pairs the output-pixel dimension: f32x2 accumulators, sliding
// pair table Q[0..6] per input row, uniform weight splat -> v_pk_fma_f32.
// Exact f32 math; worst case lowers to 2x v_fma_f32 (neutral).

#define CT 256

typedef float f32x2 __attribute__((ext_vector_type(2)));
typedef float f32x4 __attribute__((ext_vector_type(4)));

static __device__ __forceinline__ unsigned short f2bf(float f) {
    __hip_bfloat16 h = __float2bfloat16(f);
    return *reinterpret_cast<unsigned short*>(&h);
}
static __device__ __forceinline__ float bf2f(unsigned short u) {
    __hip_bfloat16 h;
    *reinterpret_cast<unsigned short*>(&h) = u;
    return __bfloat162float(h);
}

// ---------------- split-path conv kernel ----------------
template<bool IN_BF16, int OC, bool POOL>
__global__ __launch_bounds__(CT) void conv_stage(
    const void* __restrict__ in_,
    const float* __restrict__ w, const float* __restrict__ bias,
    unsigned short* __restrict__ out_, float* __restrict__ feat)
{
    const int tx = blockIdx.x;     // 0..3   (x tiles of 64)
    const int ty = blockIdx.y;     // 0..7   (y tiles of 32)
    const int b  = blockIdx.z;     // image
    const int tid = threadIdx.x;

    __shared__ __align__(16) float sIn[3 * 36 * 68];   // 29376 B
    __shared__ float sPartial[16];

    const int gy0 = ty * 32, gx0 = tx * 64;

    // ---- stage 36 rows x 68 cols x 3 ch (zero-padded) ----
    for (int pos = tid; pos < 36 * 34; pos += CT) {
        const int r  = pos / 34;
        const int k  = pos - r * 34;
        const int gy = gy0 - 2 + r;
        const int gx = gx0 - 2 + 2 * k;
        const bool yok = (unsigned)gy < 256u;
        const bool full = yok & (gx >= 0) & (gx + 1 < 256);
#pragma unroll
        for (int c = 0; c < 3; ++c) {
            float2 v = make_float2(0.f, 0.f);
            if (!IN_BF16) {
                const float* src = (const float*)in_ + (((size_t)b * 3 + c) * 256 + gy) * 256;
                if (full) {
                    v = *reinterpret_cast<const float2*>(src + gx);
                } else if (yok) {
                    if ((unsigned)gx < 256u)       v.x = src[gx];
                    if ((unsigned)(gx + 1) < 256u) v.y = src[gx + 1];
                }
            } else {
                const unsigned short* src =
                    (const unsigned short*)in_ + (((size_t)b * 3 + c) * 256 + gy) * 256;
                if (full) {
                    const unsigned int u = *reinterpret_cast<const unsigned int*>(src + gx);
                    v.x = bf2f((unsigned short)(u & 0xffffu));
                    v.y = bf2f((unsigned short)(u >> 16));
                } else if (yok) {
                    if ((unsigned)gx < 256u)       v.x = bf2f(src[gx]);
                    if ((unsigned)(gx + 1) < 256u) v.y = bf2f(src[gx + 1]);
                }
            }
            *reinterpret_cast<float2*>(&sIn[(c * 36 + r) * 68 + 2 * k]) = v;
        }
    }
    __syncthreads();

    // ---- compute: task (ry,qx), 2 rows x 4 cols x OC; packed f32x2 ----
    const int ry = tid >> 4, qx = tid & 15;
    const int y0 = ry * 2,  x0 = qx * 4;

    // acc0 = output row y0, acc1 = output row y0+1; lo=(p0,p1), hi=(p2,p3)
    f32x2 a0l[OC], a0h[OC], a1l[OC], a1h[OC];
#pragma unroll
    for (int c = 0; c < OC; ++c) {
        const float bb = bias[c];
        const f32x2 bb2 = {bb, bb};
        a0l[c] = bb2; a0h[c] = bb2; a1l[c] = bb2; a1h[c] = bb2;
    }

#pragma unroll
    for (int ic = 0; ic < 3; ++ic) {
        const float* base = &sIn[ic * 2448 + y0 * 68 + x0];
#pragma unroll
        for (int rw = 0; rw < 6; ++rw) {
            const f32x4 a4 = *reinterpret_cast<const f32x4*>(base + rw * 68);
            const f32x4 b4 = *reinterpret_cast<const f32x4*>(base + rw * 68 + 4);
            // sliding pair table: Q[k] = (v[k], v[k+1]) over the 8-wide window
            f32x2 Q[7];
            Q[0] = __builtin_shufflevector(a4, b4, 0, 1);
            Q[1] = __builtin_shufflevector(a4, b4, 1, 2);
            Q[2] = __builtin_shufflevector(a4, b4, 2, 3);
            Q[3] = __builtin_shufflevector(a4, b4, 3, 4);
            Q[4] = __builtin_shufflevector(a4, b4, 4, 5);
            Q[5] = __builtin_shufflevector(a4, b4, 5, 6);
            Q[6] = __builtin_shufflevector(a4, b4, 6, 7);

#pragma unroll
            for (int kx = 0; kx < 5; ++kx) {
#pragma unroll
                for (int c = 0; c < OC; ++c) {
                    if (rw < 5) {               // ky = rw feeds output row 0
                        const float wv = w[((c * 3 + ic) * 5 + rw) * 5 + kx];
                        const f32x2 ws = {wv, wv};
                        a0l[c] = __builtin_elementwise_fma(Q[kx],     ws, a0l[c]);
                        a0h[c] = __builtin_elementwise_fma(Q[kx + 2], ws, a0h[c]);
                    }
                    if (rw >= 1) {              // ky = rw-1 feeds output row 1
                        const float wv = w[((c * 3 + ic) * 5 + (rw - 1)) * 5 + kx];
                        const f32x2 ws = {wv, wv};
                        a1l[c] = __builtin_elementwise_fma(Q[kx],     ws, a1l[c]);
                        a1h[c] = __builtin_elementwise_fma(Q[kx + 2], ws, a1h[c]);
                    }
                }
            }
        }
    }

    if (!POOL) {
#pragma unroll
        for (int rr = 0; rr < 2; ++rr) {
            const int gy = gy0 + y0 + rr;
#pragma unroll
            for (int c = 0; c < OC; ++c) {
                const f32x2 lo2 = (rr == 0) ? a0l[c] : a1l[c];
                const f32x2 hi2 = (rr == 0) ? a0h[c] : a1h[c];
                const unsigned int lo =
                    (unsigned int)f2bf(fmaxf(lo2[0], 0.f)) |
                    ((unsigned int)f2bf(fmaxf(lo2[1], 0.f)) << 16);
                const unsigned int hi =
                    (unsigned int)f2bf(fmaxf(hi2[0], 0.f)) |
                    ((unsigned int)f2bf(fmaxf(hi2[1], 0.f)) << 16);
                unsigned short* dst =
                    out_ + (((size_t)b * OC + c) * 256 + gy) * 256 + gx0 + x0;
                *reinterpret_cast<uint2*>(dst) = make_uint2(lo, hi);
            }
        }
    } else {
        float s = fmaxf(a0l[0][0], 0.f) + fmaxf(a0l[0][1], 0.f)
                + fmaxf(a0h[0][0], 0.f) + fmaxf(a0h[0][1], 0.f)
                + fmaxf(a1l[0][0], 0.f) + fmaxf(a1l[0][1], 0.f)
                + fmaxf(a1h[0][0], 0.f) + fmaxf(a1h[0][1], 0.f);
        // butterfly over the 16 lanes sharing a patch (qx bits 0-1, ry bits 0-1)
        s += __shfl_xor(s, 1, 64);
        s += __shfl_xor(s, 2, 64);
        s += __shfl_xor(s, 16, 64);
        s += __shfl_xor(s, 32, 64);
        const int wv = tid >> 6, l = tid & 63;
        if ((l & 3) == 0 && l < 16) sPartial[wv * 4 + (l >> 2)] = s;
        __syncthreads();
        if (tid < 8) {
            const int py = tid >> 2, px = tid & 3;
            const float v2 = sPartial[(2 * py) * 4 + px] + sPartial[(2 * py + 1) * 4 + px];
            const int j = ty * 2 + py, i = tx * 4 + px;
            feat[(size_t)b * 256 + j * 16 + i] = v2 * (1.f / 256.f);
        }
    }
}

// ---------------- fused fallback (round-3 kernel) ----------------
#define NTHREADS 512

template<int ICn, int OCn, int OW, int OH, int IS, int ICSZ, int OS, int OCSZ, bool MASK>
__device__ __forceinline__ void conv5x5(
    const float* __restrict__ sin, float* __restrict__ sout,
    const float* __restrict__ w, const float* __restrict__ bias,
    int gy0, int gx0, int tid)
{
    constexpr int QX = OW / 4;
    constexpr int RY = OH / 2;
    constexpr int TASKS = QX * RY;
    if (tid < TASKS) {
        const int ry = tid / QX;
        const int qx = tid - ry * QX;
        const int y0 = ry * 2, x0 = qx * 4;
        float acc[2][OCn][4];
#pragma unroll
        for (int c = 0; c < OCn; ++c) {
            const float bb = bias[c];
#pragma unroll
            for (int p = 0; p < 4; ++p) { acc[0][c][p] = bb; acc[1][c][p] = bb; }
        }
#pragma unroll
        for (int ic = 0; ic < ICn; ++ic) {
            const float* base = sin + ic * ICSZ + y0 * IS + x0;
#pragma unroll
            for (int r = 0; r < 6; ++r) {
                const float4 a4 = *reinterpret_cast<const float4*>(base + r * IS);
                const float4 b4 = *reinterpret_cast<const float4*>(base + r * IS + 4);
                const float v[8] = {a4.x, a4.y, a4.z, a4.w, b4.x, b4.y, b4.z, b4.w};
#pragma unroll
                for (int kx = 0; kx < 5; ++kx)
#pragma unroll
                    for (int c = 0; c < OCn; ++c) {
                        if (r < 5) {
                            const float wv = w[((c * ICn + ic) * 5 + r) * 5 + kx];
#pragma unroll
                            for (int p = 0; p < 4; ++p)
                                acc[0][c][p] = fmaf(v[p + kx], wv, acc[0][c][p]);
                        }
                        if (r >= 1) {
                            const float wv = w[((c * ICn + ic) * 5 + (r - 1)) * 5 + kx];
#pragma unroll
                            for (int p = 0; p < 4; ++p)
                                acc[1][c][p] = fmaf(v[p + kx], wv, acc[1][c][p]);
                        }
                    }
            }
        }
#pragma unroll
        for (int rr = 0; rr < 2; ++rr) {
            const int gy = gy0 + y0 + rr;
#pragma unroll
            for (int c = 0; c < OCn; ++c) {
                float o[4];
#pragma unroll
                for (int p = 0; p < 4; ++p) {
                    float rv = fmaxf(acc[rr][c][p], 0.f);
                    if (MASK) {
                        const int gx = gx0 + x0 + p;
                        const bool ok = ((unsigned)gy < 256u) & ((unsigned)gx < 256u);
                        rv = ok ? rv : 0.f;
                    }
                    o[p] = rv;
                }
                *reinterpret_cast<float4*>(&sout[c * OCSZ + (y0 + rr) * OS + x0]) =
                    make_float4(o[0], o[1], o[2], o[3]);
            }
        }
    }
}

__global__ __launch_bounds__(NTHREADS) void fused_conv_feat(
    const float* __restrict__ x,
    const float* __restrict__ w1, const float* __restrict__ b1,
    const float* __restrict__ w2, const float* __restrict__ b2,
    const float* __restrict__ w3, const float* __restrict__ b3,
    float* __restrict__ feat)
{
    const int tile = blockIdx.x;
    const int b    = blockIdx.y;
    const int tx   = tile & 3, ty = tile >> 2;
    const int tid  = threadIdx.x;

    __shared__ __align__(16) float lds[10032 + 9120];
    float* sIn = lds;
    float* sH1 = lds + 10032;
    float* sH2 = lds;
    float* sH3 = lds + 10032;

    const int gy0s = ty * 32 - 6, gx0s = tx * 64 - 6;
    for (int i = tid; i < 3 * 44 * 38; i += NTHREADS) {
        const int c   = i / 1672;
        const int rem = i - c * 1672;
        const int r   = rem / 38;
        const int k   = rem - r * 38;
        const int gy = gy0s + r, gx = gx0s + 2 * k;
        float2 v = make_float2(0.f, 0.f);
        if ((unsigned)gy < 256u) {
            const float* src = x + (((size_t)b * 3 + c) * 256 + gy) * 256;
            if (gx >= 0 && gx + 1 < 256) {
                v = *reinterpret_cast<const float2*>(src + gx);
            } else {
                if ((unsigned)gx < 256u)       v.x = src[gx];
                if ((unsigned)(gx + 1) < 256u) v.y = src[gx + 1];
            }
        }
        *reinterpret_cast<float2*>(&sIn[c * 3344 + r * 76 + 2 * k]) = v;
    }
    __syncthreads();

    conv5x5<3, 3, 72, 40, 76, 3344, 76, 3040, true>(sIn, sH1, w1, b1,
                                                    ty * 32 - 4, tx * 64 - 4, tid);
    __syncthreads();
    conv5x5<3, 3, 68, 36, 76, 3040, 76, 2736, true>(sH1, sH2, w2, b2,
                                                    ty * 32 - 2, tx * 64 - 2, tid);
    __syncthreads();
    conv5x5<3, 1, 64, 32, 76, 2736, 64, 2048, false>(sH2, sH3, w3, b3, 0, 0, tid);
    __syncthreads();

    const int wv   = tid >> 6;
    const int lane = tid & 63;
    const int py = wv >> 2, px = wv & 3;
    float s = 0.f;
#pragma unroll
    for (int k = 0; k < 4; ++k) {
        const int idx = lane + k * 64;
        const int r = idx >> 4, cc = idx & 15;
        s += sH3[(py * 16 + r) * 64 + px * 16 + cc];
    }
#pragma unroll
    for (int off = 32; off > 0; off >>= 1) s += __shfl_down(s, off, 64);
    if (lane == 0) {
        const int j = ty * 2 + py, i = tx * 4 + px;
        feat[(size_t)b * 256 + j * 16 + i] = s * (1.f / 256.f);
    }
}

// ---------------- MLP head ----------------
__global__ __launch_bounds__(64) void mlp_head(
    const float* __restrict__ feat,
    const float* __restrict__ wl1, const float* __restrict__ bl1,
    const float* __restrict__ wl2, const float* __restrict__ bl2,
    float* __restrict__ out)
{
    const int b = blockIdx.x;
    const int t = threadIdx.x;

    __shared__ float sF[256];
    __shared__ float sE[64];
    __shared__ float sL[8];
    __shared__ float sX[8];

    for (int i = t; i < 256; i += 64) sF[i] = feat[(size_t)b * 256 + i];
    __syncthreads();

    float acc = bl1[t];
    for (int k = 0; k < 256; ++k) acc = fmaf(sF[k], wl1[t * 256 + k], acc);
    sE[t] = acc;
    __syncthreads();

    if (t < 8) {
        float l = bl2[t];
#pragma unroll
        for (int k = 0; k < 64; ++k) l = fmaf(sE[k], wl2[t * 64 + k], l);
        sL[t] = l;
    }
    __syncthreads();

    if (t < 8) {
        float m = sL[0];
#pragma unroll
        for (int k = 1; k < 8; ++k) m = fmaxf(m, sL[k]);
        sX[t] = __expf(sL[t] - m);
    }
    __syncthreads();

    if (t < 8) {
        float sum = 0.f;
#pragma unroll
        for (int k = 0; k < 8; ++k) sum += sX[k];
        out[(size_t)b * 8 + t] = sX[t] / sum;
    }
}

extern "C" void kernel_launch(void* const* d_in, const int* in_sizes, int n_in,
                              void* d_out, int out_size, void* d_ws, size_t ws_size,
                              hipStream_t stream) {
    const float* x   = (const float*)d_in[0];
    const float* w1  = (const float*)d_in[1];
    const float* b1  = (const float*)d_in[2];
    const float* w2  = (const float*)d_in[3];
    const float* b2  = (const float*)d_in[4];
    const float* w3  = (const float*)d_in[5];
    const float* b3  = (const float*)d_in[6];
    const float* wl1 = (const float*)d_in[7];
    const float* bl1 = (const float*)d_in[8];
    const float* wl2 = (const float*)d_in[9];
    const float* bl2 = (const float*)d_in[10];
    float* out  = (float*)d_out;

    const size_t FEAT_B = 256u * 256u * 4u;                 // 262144
    const size_t H_B    = (size_t)256 * 3 * 256 * 256 * 2;  // 100663296
    float* feat = (float*)d_ws;

    if (ws_size >= FEAT_B + 2 * H_B) {
        unsigned short* h1 = (unsigned short*)((char*)d_ws + FEAT_B);
        unsigned short* h2 = (unsigned short*)((char*)d_ws + FEAT_B + H_B);
        dim3 g(4, 8, 256);
        conv_stage<false, 3, false><<<g, CT, 0, stream>>>(x,  w1, b1, h1, nullptr);
        conv_stage<true,  3, false><<<g, CT, 0, stream>>>(h1, w2, b2, h2, nullptr);
        conv_stage<true,  1, true ><<<g, CT, 0, stream>>>(h2, w3, b3, nullptr, feat);
    } else {
        dim3 g1(32, 256);
        fused_conv_feat<<<g1, NTHREADS, 0, stream>>>(x, w1, b1, w2, b2, w3, b3, feat);
    }
    mlp_head<<<256, 64, 0, stream>>>(feat, wl1, bl1, wl2, bl2, out);
}